// Round 1
// baseline (720.242 us; speedup 1.0000x reference)
//
#include <hip/hip_runtime.h>
#include <math.h>

#define LN_EPS 1e-5f

// ---------- CSR build ----------
__global__ __launch_bounds__(256) void k_init(int* cnt, int N) {
    int i = blockIdx.x * 256 + threadIdx.x;
    if (i < N) cnt[i] = 0;
}

__global__ __launch_bounds__(256) void k_count(const int* __restrict__ ei, int* __restrict__ cnt, int E) {
    int e = blockIdx.x * 256 + threadIdx.x;
    if (e < E) atomicAdd(&cnt[ei[E + e]], 1);   // col = target
}

__global__ __launch_bounds__(256) void k_scan_block(const int* __restrict__ cnt, int* __restrict__ rowptr,
                                                    int* __restrict__ bsums, int N) {
    __shared__ int s[256];
    int t = threadIdx.x;
    int gid = blockIdx.x * 256 + t;
    int v = (gid < N) ? cnt[gid] : 0;
    s[t] = v;
    __syncthreads();
    int val = v;
    for (int off = 1; off < 256; off <<= 1) {
        int add = (t >= off) ? s[t - off] : 0;
        __syncthreads();
        val += add;
        s[t] = val;
        __syncthreads();
    }
    if (gid < N) rowptr[gid] = val - v;          // exclusive within block
    if (t == 255) bsums[blockIdx.x] = val;       // block total
}

__global__ __launch_bounds__(512) void k_scan_sums(int* bsums, int NB) {
    __shared__ int s[512];
    int t = threadIdx.x;
    if (NB > 512) {                              // generic fallback (not hit at N=100k)
        if (t == 0) { int run = 0; for (int i = 0; i < NB; ++i) { int v = bsums[i]; bsums[i] = run; run += v; } }
        return;
    }
    int v = (t < NB) ? bsums[t] : 0;
    s[t] = v;
    __syncthreads();
    int val = v;
    for (int off = 1; off < 512; off <<= 1) {
        int add = (t >= off) ? s[t - off] : 0;
        __syncthreads();
        val += add;
        s[t] = val;
        __syncthreads();
    }
    if (t < NB) bsums[t] = val - v;              // exclusive
}

__global__ __launch_bounds__(256) void k_finalize(const int* __restrict__ cnt, int* __restrict__ rowptr,
                                                  const int* __restrict__ bsums, int* __restrict__ cursor,
                                                  float* __restrict__ dinv, int N) {
    int i = blockIdx.x * 256 + threadIdx.x;
    if (i < N) {
        int r = rowptr[i] + bsums[i >> 8];
        rowptr[i] = r;
        cursor[i] = r;
        dinv[i] = rsqrtf((float)(cnt[i] + 1));   // +1 self-loop; deg >= 1 always
    }
}

__global__ __launch_bounds__(256) void k_fill(const int* __restrict__ ei, int* __restrict__ cursor,
                                              int* __restrict__ srcidx, int E) {
    int e = blockIdx.x * 256 + threadIdx.x;
    if (e < E) {
        int c = ei[E + e];
        int p = atomicAdd(&cursor[c], 1);
        srcidx[p] = ei[e];                       // source node
    }
}

// ---------- h = x @ W (fp32, vector ALU) ----------
// block 256 = 8 rows x 32 lanes; each thread computes a float4 of one row.
__global__ __launch_bounds__(256) void k_gemm(const float* __restrict__ x, const float* __restrict__ W,
                                              float* __restrict__ h, int N) {
    int tid = threadIdx.x;
    int lane = tid & 31;
    int rsub = tid >> 5;
    int row = blockIdx.x * 8 + rsub;
    if (row >= N) return;
    const float4* x4 = (const float4*)(x + (size_t)row * 128);
    const float4* W4 = (const float4*)W;         // W[k][m] row-major: 32 float4 per k-row
    float4 acc = make_float4(0.f, 0.f, 0.f, 0.f);
#pragma unroll 4
    for (int k4 = 0; k4 < 32; ++k4) {
        float4 xv = x4[k4];
        float4 w0 = W4[(k4 * 4 + 0) * 32 + lane];
        float4 w1 = W4[(k4 * 4 + 1) * 32 + lane];
        float4 w2 = W4[(k4 * 4 + 2) * 32 + lane];
        float4 w3 = W4[(k4 * 4 + 3) * 32 + lane];
        acc.x += xv.x * w0.x + xv.y * w1.x + xv.z * w2.x + xv.w * w3.x;
        acc.y += xv.x * w0.y + xv.y * w1.y + xv.z * w2.y + xv.w * w3.y;
        acc.z += xv.x * w0.z + xv.y * w1.z + xv.z * w2.z + xv.w * w3.z;
        acc.w += xv.x * w0.w + xv.y * w1.w + xv.z * w2.w + xv.w * w3.w;
    }
    ((float4*)h)[(size_t)row * 32 + lane] = acc;
}

// ---------- fused aggregate + bias + LayerNorm + ReLU ----------
// one wave (64 lanes) per node; each lane owns 2 channels (float2).
__global__ __launch_bounds__(256) void k_agg_ln(const float* __restrict__ hbuf, const int* __restrict__ srcidx,
                                                const int* __restrict__ rowptr, const int* __restrict__ cnt,
                                                const float* __restrict__ dinv, const float* __restrict__ bias,
                                                const float* __restrict__ gamma, const float* __restrict__ beta,
                                                float* __restrict__ out, int N) {
    int wid = (int)((blockIdx.x * (unsigned)blockDim.x + threadIdx.x) >> 6);
    int lane = threadIdx.x & 63;
    if (wid >= N) return;
    float di = dinv[wid];
    const float2* h2 = (const float2*)hbuf;
    float2 v = h2[(size_t)wid * 64 + lane];
    float ax = di * v.x, ay = di * v.y;          // self-loop term (pre-scale by di)
    int start = rowptr[wid];
    int end = start + cnt[wid];
    for (int e = start; e < end; ++e) {
        int j = srcidx[e];
        float s = dinv[j];
        float2 hv = h2[(size_t)j * 64 + lane];
        ax += s * hv.x;
        ay += s * hv.y;
    }
    int c0 = lane * 2;
    float vx = ax * di + bias[c0];
    float vy = ay * di + bias[c0 + 1];
    // LayerNorm over 128 channels spread as float2 across 64 lanes
    float sum = vx + vy, sq = vx * vx + vy * vy;
#pragma unroll
    for (int off = 32; off > 0; off >>= 1) {
        sum += __shfl_xor(sum, off, 64);
        sq += __shfl_xor(sq, off, 64);
    }
    float mu = sum * (1.0f / 128.0f);
    float var = sq * (1.0f / 128.0f) - mu * mu;
    float rstd = rsqrtf(var + LN_EPS);
    float o0 = (vx - mu) * rstd * gamma[c0] + beta[c0];
    float o1 = (vy - mu) * rstd * gamma[c0 + 1] + beta[c0 + 1];
    o0 = fmaxf(o0, 0.f);
    o1 = fmaxf(o1, 0.f);
    ((float2*)out)[(size_t)wid * 64 + lane] = make_float2(o0, o1);
}

extern "C" void kernel_launch(void* const* d_in, const int* in_sizes, int n_in,
                              void* d_out, int out_size, void* d_ws, size_t ws_size,
                              hipStream_t stream) {
    const float* x = (const float*)d_in[0];
    const int* ei = (const int*)d_in[1];
    const float* W = (const float*)d_in[2];
    const float* bias = (const float*)d_in[3];
    const float* gamma = (const float*)d_in[4];
    const float* beta = (const float*)d_in[5];
    float* out = (float*)d_out;

    int N = in_sizes[0] / 128;
    int E = in_sizes[1] / 2;
    int NB = (N + 255) / 256;

    // workspace carve-up (256B-aligned): ~59 MB total
    char* p = (char*)d_ws;
    auto alloc = [&](size_t bytes) {
        char* r = p;
        p += (bytes + 255) & ~(size_t)255;
        return r;
    };
    int* cnt = (int*)alloc((size_t)N * 4);
    int* rowptr = (int*)alloc((size_t)N * 4);
    int* cursor = (int*)alloc((size_t)N * 4);
    float* dinv = (float*)alloc((size_t)N * 4);
    int* bsums = (int*)alloc((size_t)NB * 4);
    int* srcidx = (int*)alloc((size_t)E * 4);
    float* hbuf = (float*)alloc((size_t)N * 128 * 4);

    k_init<<<NB, 256, 0, stream>>>(cnt, N);
    k_count<<<(E + 255) / 256, 256, 0, stream>>>(ei, cnt, E);
    k_scan_block<<<NB, 256, 0, stream>>>(cnt, rowptr, bsums, N);
    k_scan_sums<<<1, 512, 0, stream>>>(bsums, NB);
    k_finalize<<<NB, 256, 0, stream>>>(cnt, rowptr, bsums, cursor, dinv, N);
    k_fill<<<(E + 255) / 256, 256, 0, stream>>>(ei, cursor, srcidx, E);
    k_gemm<<<(N + 7) / 8, 256, 0, stream>>>(x, W, hbuf, N);
    k_agg_ln<<<(N + 3) / 4, 256, 0, stream>>>(hbuf, srcidx, rowptr, cnt, dinv, bias, gamma, beta, out, N);
}

// Round 2
// 471.354 us; speedup vs baseline: 1.5280x; 1.5280x over previous
//
#include <hip/hip_runtime.h>
#include <math.h>

#define LN_EPS 1e-5f

// ---------- CSR build ----------
__global__ __launch_bounds__(256) void k_init(int* cnt, int N) {
    int i = blockIdx.x * 256 + threadIdx.x;
    if (i < N) cnt[i] = 0;
}

__global__ __launch_bounds__(256) void k_count(const int* __restrict__ ei, int* __restrict__ cnt, int E) {
    int e = blockIdx.x * 256 + threadIdx.x;
    if (e < E) atomicAdd(&cnt[ei[E + e]], 1);   // col = target
}

__global__ __launch_bounds__(256) void k_scan_block(const int* __restrict__ cnt, int* __restrict__ rowptr,
                                                    int* __restrict__ bsums, int N) {
    __shared__ int s[256];
    int t = threadIdx.x;
    int gid = blockIdx.x * 256 + t;
    int v = (gid < N) ? cnt[gid] : 0;
    s[t] = v;
    __syncthreads();
    int val = v;
    for (int off = 1; off < 256; off <<= 1) {
        int add = (t >= off) ? s[t - off] : 0;
        __syncthreads();
        val += add;
        s[t] = val;
        __syncthreads();
    }
    if (gid < N) rowptr[gid] = val - v;          // exclusive within block
    if (t == 255) bsums[blockIdx.x] = val;       // block total
}

__global__ __launch_bounds__(512) void k_scan_sums(int* bsums, int NB) {
    __shared__ int s[512];
    int t = threadIdx.x;
    if (NB > 512) {                              // generic fallback (not hit at N=100k)
        if (t == 0) { int run = 0; for (int i = 0; i < NB; ++i) { int v = bsums[i]; bsums[i] = run; run += v; } }
        return;
    }
    int v = (t < NB) ? bsums[t] : 0;
    s[t] = v;
    __syncthreads();
    int val = v;
    for (int off = 1; off < 512; off <<= 1) {
        int add = (t >= off) ? s[t - off] : 0;
        __syncthreads();
        val += add;
        s[t] = val;
        __syncthreads();
    }
    if (t < NB) bsums[t] = val - v;              // exclusive
}

__global__ __launch_bounds__(256) void k_finalize(const int* __restrict__ cnt, int* __restrict__ rowptr,
                                                  const int* __restrict__ bsums, int* __restrict__ cursor,
                                                  float* __restrict__ dinv, int N) {
    int i = blockIdx.x * 256 + threadIdx.x;
    if (i < N) {
        int r = rowptr[i] + bsums[i >> 8];
        rowptr[i] = r;
        cursor[i] = r;
        dinv[i] = rsqrtf((float)(cnt[i] + 1));   // +1 self-loop; deg >= 1 always
    }
}

__global__ __launch_bounds__(256) void k_fill(const int* __restrict__ ei, int* __restrict__ cursor,
                                              int* __restrict__ srcidx, int E) {
    int e = blockIdx.x * 256 + threadIdx.x;
    if (e < E) {
        int c = ei[E + e];
        int p = atomicAdd(&cursor[c], 1);
        srcidx[p] = ei[e];                       // source node
    }
}

// ---------- g = (x @ W) * dinv[row]  (fp32, vector ALU, LDS x-tile) ----------
// block 256 = 64 rows; thread = (grp = tid>>5 -> 8 rows, lane = tid&31 -> 4 cols).
// Each thread computes 8 rows x 4 cols, amortizing W reads 8x vs round 1.
__global__ __launch_bounds__(256) void k_gemm(const float* __restrict__ x, const float* __restrict__ W,
                                              const float* __restrict__ dinv, float* __restrict__ g, int N) {
    __shared__ float4 xs[64][32];                // 32 KB x-tile
    int tid = threadIdx.x;
    int row0 = blockIdx.x * 64;
    int rows = min(64, N - row0);
    const float4* xg = (const float4*)x + (size_t)row0 * 32;
#pragma unroll
    for (int i = 0; i < 8; ++i) {
        int idx = tid + i * 256;                 // idx = r*32 + c4
        if ((idx >> 5) < rows) xs[idx >> 5][idx & 31] = xg[idx];
    }
    __syncthreads();
    int lane = tid & 31;
    int grp = tid >> 5;
    const float4* W4 = (const float4*)W;         // W[k][m] row-major: 32 float4 per k-row
    float4 acc[8];
#pragma unroll
    for (int r = 0; r < 8; ++r) acc[r] = make_float4(0.f, 0.f, 0.f, 0.f);
    for (int k4 = 0; k4 < 32; ++k4) {
        float4 w0 = W4[(k4 * 4 + 0) * 32 + lane];
        float4 w1 = W4[(k4 * 4 + 1) * 32 + lane];
        float4 w2 = W4[(k4 * 4 + 2) * 32 + lane];
        float4 w3 = W4[(k4 * 4 + 3) * 32 + lane];
#pragma unroll
        for (int r = 0; r < 8; ++r) {
            float4 xv = xs[grp * 8 + r][k4];     // broadcast within half-wave: conflict-free
            acc[r].x += xv.x * w0.x + xv.y * w1.x + xv.z * w2.x + xv.w * w3.x;
            acc[r].y += xv.x * w0.y + xv.y * w1.y + xv.z * w2.y + xv.w * w3.y;
            acc[r].z += xv.x * w0.z + xv.y * w1.z + xv.z * w2.z + xv.w * w3.z;
            acc[r].w += xv.x * w0.w + xv.y * w1.w + xv.z * w2.w + xv.w * w3.w;
        }
    }
#pragma unroll
    for (int r = 0; r < 8; ++r) {
        int row = row0 + grp * 8 + r;
        if (row < N) {
            float s = dinv[row];                 // pre-scale: g = h * dinv (folds per-edge mul away)
            float4 o = acc[r];
            o.x *= s; o.y *= s; o.z *= s; o.w *= s;
            ((float4*)g)[(size_t)row * 32 + lane] = o;
        }
    }
}

// ---------- fused aggregate + bias + LayerNorm + ReLU ----------
// one wave (64 lanes) per node; each lane owns 2 channels (float2).
// g is pre-scaled by dinv[src], so: out[i] = dinv[i]*(g[i] + sum_{j->i} g[j]) + b
__global__ __launch_bounds__(256) void k_agg_ln(const float* __restrict__ g, const int* __restrict__ srcidx,
                                                const int* __restrict__ rowptr, const int* __restrict__ cnt,
                                                const float* __restrict__ dinv, const float* __restrict__ bias,
                                                const float* __restrict__ gamma, const float* __restrict__ beta,
                                                float* __restrict__ out, int N) {
    int wid = (int)((blockIdx.x * 256u + threadIdx.x) >> 6);
    int lane = threadIdx.x & 63;
    if (wid >= N) return;
    const float2* g2 = (const float2*)g;
    float2 self = g2[(size_t)wid * 64 + lane];   // self-loop term (already dinv-scaled)
    float ax = self.x, ay = self.y;
    int start = rowptr[wid];
    int end = start + cnt[wid];
    int e = start;
    for (; e + 4 <= end; e += 4) {               // 4 independent gathers in flight
        int j0 = srcidx[e], j1 = srcidx[e + 1], j2 = srcidx[e + 2], j3 = srcidx[e + 3];
        float2 a0 = g2[(size_t)j0 * 64 + lane];
        float2 a1 = g2[(size_t)j1 * 64 + lane];
        float2 a2 = g2[(size_t)j2 * 64 + lane];
        float2 a3 = g2[(size_t)j3 * 64 + lane];
        ax += (a0.x + a1.x) + (a2.x + a3.x);
        ay += (a0.y + a1.y) + (a2.y + a3.y);
    }
    for (; e < end; ++e) {
        int j = srcidx[e];
        float2 a = g2[(size_t)j * 64 + lane];
        ax += a.x;
        ay += a.y;
    }
    float di = dinv[wid];
    int c0 = lane * 2;
    float vx = ax * di + bias[c0];
    float vy = ay * di + bias[c0 + 1];
    // LayerNorm over 128 channels spread as float2 across 64 lanes
    float sum = vx + vy, sq = vx * vx + vy * vy;
#pragma unroll
    for (int off = 32; off > 0; off >>= 1) {
        sum += __shfl_xor(sum, off, 64);
        sq += __shfl_xor(sq, off, 64);
    }
    float mu = sum * (1.0f / 128.0f);
    float var = sq * (1.0f / 128.0f) - mu * mu;
    float rstd = rsqrtf(var + LN_EPS);
    float o0 = fmaxf((vx - mu) * rstd * gamma[c0] + beta[c0], 0.f);
    float o1 = fmaxf((vy - mu) * rstd * gamma[c0 + 1] + beta[c0 + 1], 0.f);
    ((float2*)out)[(size_t)wid * 64 + lane] = make_float2(o0, o1);
}

extern "C" void kernel_launch(void* const* d_in, const int* in_sizes, int n_in,
                              void* d_out, int out_size, void* d_ws, size_t ws_size,
                              hipStream_t stream) {
    const float* x = (const float*)d_in[0];
    const int* ei = (const int*)d_in[1];
    const float* W = (const float*)d_in[2];
    const float* bias = (const float*)d_in[3];
    const float* gamma = (const float*)d_in[4];
    const float* beta = (const float*)d_in[5];
    float* out = (float*)d_out;

    int N = in_sizes[0] / 128;
    int E = in_sizes[1] / 2;
    int NB = (N + 255) / 256;

    // workspace carve-up (256B-aligned)
    char* p = (char*)d_ws;
    auto alloc = [&](size_t bytes) {
        char* r = p;
        p += (bytes + 255) & ~(size_t)255;
        return r;
    };
    int* cnt = (int*)alloc((size_t)N * 4);
    int* rowptr = (int*)alloc((size_t)N * 4);
    int* cursor = (int*)alloc((size_t)N * 4);
    float* dinv = (float*)alloc((size_t)N * 4);
    int* bsums = (int*)alloc((size_t)NB * 4);
    int* srcidx = (int*)alloc((size_t)E * 4);
    float* gbuf = (float*)alloc((size_t)N * 128 * 4);

    k_init<<<NB, 256, 0, stream>>>(cnt, N);
    k_count<<<(E + 255) / 256, 256, 0, stream>>>(ei, cnt, E);
    k_scan_block<<<NB, 256, 0, stream>>>(cnt, rowptr, bsums, N);
    k_scan_sums<<<1, 512, 0, stream>>>(bsums, NB);
    k_finalize<<<NB, 256, 0, stream>>>(cnt, rowptr, bsums, cursor, dinv, N);
    k_fill<<<(E + 255) / 256, 256, 0, stream>>>(ei, cursor, srcidx, E);
    k_gemm<<<(N + 63) / 64, 256, 0, stream>>>(x, W, dinv, gbuf, N);
    k_agg_ln<<<(N + 3) / 4, 256, 0, stream>>>(gbuf, srcidx, rowptr, cnt, dinv, bias, gamma, beta, out, N);
}

// Round 3
// 323.024 us; speedup vs baseline: 2.2297x; 1.4592x over previous
//
#include <hip/hip_runtime.h>
#include <math.h>

#define LN_EPS 1e-5f
// Bucket = 256 destination nodes. Requires N <= 2^20 (src packs in 20 bits)
// and NBUCK <= 512 (scan/hist arrays). N=100k -> NBUCK=391. [problem-fixed]

__global__ __launch_bounds__(256) void k_zero(int* p, int n) {
    int i = blockIdx.x * 256 + threadIdx.x;
    if (i < n) p[i] = 0;
}

// ---- Phase A: bucket histogram (LDS-staged, ~200k global atomics total) ----
__global__ __launch_bounds__(256) void k_bucket_hist(const int* __restrict__ ei, int* __restrict__ bucketCnt,
                                                     int E, int chunk) {
    __shared__ int h[512];
    for (int i = threadIdx.x; i < 512; i += 256) h[i] = 0;
    __syncthreads();
    int e0 = blockIdx.x * chunk;
    int e1 = min(e0 + chunk, E);
    for (int e = e0 + threadIdx.x; e < e1; e += 256)
        atomicAdd(&h[ei[E + e] >> 8], 1);        // LDS atomic
    __syncthreads();
    for (int i = threadIdx.x; i < 512; i += 256)
        if (h[i]) atomicAdd(&bucketCnt[i], h[i]);
}

// ---- scan bucket counts -> bucketOfs (exclusive), bucketCursor copy ----
__global__ __launch_bounds__(512) void k_scan_buckets(const int* __restrict__ bucketCnt, int* __restrict__ bucketOfs,
                                                      int* __restrict__ bucketCursor, int NBUCK, int E) {
    __shared__ int s[512];
    int t = threadIdx.x;
    int v = (t < NBUCK) ? bucketCnt[t] : 0;
    s[t] = v;
    __syncthreads();
    int val = v;
    for (int off = 1; off < 512; off <<= 1) {
        int add = (t >= off) ? s[t - off] : 0;
        __syncthreads();
        val += add;
        s[t] = val;
        __syncthreads();
    }
    if (t < NBUCK) {
        int ex = val - v;
        bucketOfs[t] = ex;
        bucketCursor[t] = ex;
    }
    if (t == 0) bucketOfs[NBUCK] = E;
}

// ---- Phase B: partition edges into bucket regions, packed (dstLocal<<20)|src ----
__global__ __launch_bounds__(256) void k_partition(const int* __restrict__ ei, int* __restrict__ bucketCursor,
                                                   unsigned* __restrict__ pk, int E, int chunk) {
    __shared__ int h[512];
    __shared__ int base[512];
    for (int i = threadIdx.x; i < 512; i += 256) h[i] = 0;
    __syncthreads();
    int e0 = blockIdx.x * chunk;
    int e1 = min(e0 + chunk, E);
    for (int e = e0 + threadIdx.x; e < e1; e += 256)
        atomicAdd(&h[ei[E + e] >> 8], 1);
    __syncthreads();
    for (int i = threadIdx.x; i < 512; i += 256) {
        if (h[i] > 0) {
            base[i] = atomicAdd(&bucketCursor[i], h[i]);   // block-level reservation
            h[i] = 0;                                      // reuse as local rank cursor
        }
    }
    __syncthreads();
    for (int e = e0 + threadIdx.x; e < e1; e += 256) {
        int col = ei[E + e];
        int src = ei[e];
        int b = col >> 8;
        int r = atomicAdd(&h[b], 1);                       // LDS rank
        pk[base[b] + r] = ((unsigned)(col & 255) << 20) | (unsigned)src;
    }
}

// ---- Phase C: bucket -> CSR (contiguous writes), plus cnt/rowptr/dinv ----
__global__ __launch_bounds__(256) void k_csr(const unsigned* __restrict__ pk, const int* __restrict__ bucketOfs,
                                             int* __restrict__ cnt, int* __restrict__ rowptr,
                                             float* __restrict__ dinv, int* __restrict__ srcidx, int N) {
    __shared__ int lcnt[256];
    __shared__ int lofs[256];
    __shared__ int s[256];
    int b = blockIdx.x;
    int t = threadIdx.x;
    int node0 = b << 8;
    int ofs = bucketOfs[b];
    int cntb = bucketOfs[b + 1] - ofs;
    lcnt[t] = 0;
    __syncthreads();
    for (int e = t; e < cntb; e += 256)
        atomicAdd(&lcnt[pk[ofs + e] >> 20], 1);
    __syncthreads();
    int v = lcnt[t];
    s[t] = v;
    __syncthreads();
    int val = v;
    for (int off = 1; off < 256; off <<= 1) {
        int add = (t >= off) ? s[t - off] : 0;
        __syncthreads();
        val += add;
        s[t] = val;
        __syncthreads();
    }
    lofs[t] = val - v;                           // exclusive scan within bucket
    int node = node0 + t;
    if (node < N) {
        cnt[node] = v;
        rowptr[node] = ofs + lofs[t];
        dinv[node] = rsqrtf((float)(v + 1));     // +1 self-loop
    }
    lcnt[t] = 0;                                 // reuse as per-node cursor
    __syncthreads();
    for (int e = t; e < cntb; e += 256) {
        unsigned pv = pk[ofs + e];
        int d = pv >> 20;
        int r = atomicAdd(&lcnt[d], 1);
        srcidx[ofs + lofs[d] + r] = (int)(pv & 0xFFFFFu);
    }
}

// ---------- g = (x @ W) * dinv[row]  (fp32, vector ALU, LDS x-tile) ----------
__global__ __launch_bounds__(256) void k_gemm(const float* __restrict__ x, const float* __restrict__ W,
                                              const float* __restrict__ dinv, float* __restrict__ g, int N) {
    __shared__ float4 xs[64][32];                // 32 KB x-tile
    int tid = threadIdx.x;
    int row0 = blockIdx.x * 64;
    int rows = min(64, N - row0);
    const float4* xg = (const float4*)x + (size_t)row0 * 32;
#pragma unroll
    for (int i = 0; i < 8; ++i) {
        int idx = tid + i * 256;
        if ((idx >> 5) < rows) xs[idx >> 5][idx & 31] = xg[idx];
    }
    __syncthreads();
    int lane = tid & 31;
    int grp = tid >> 5;
    const float4* W4 = (const float4*)W;
    float4 acc[8];
#pragma unroll
    for (int r = 0; r < 8; ++r) acc[r] = make_float4(0.f, 0.f, 0.f, 0.f);
    for (int k4 = 0; k4 < 32; ++k4) {
        float4 w0 = W4[(k4 * 4 + 0) * 32 + lane];
        float4 w1 = W4[(k4 * 4 + 1) * 32 + lane];
        float4 w2 = W4[(k4 * 4 + 2) * 32 + lane];
        float4 w3 = W4[(k4 * 4 + 3) * 32 + lane];
#pragma unroll
        for (int r = 0; r < 8; ++r) {
            float4 xv = xs[grp * 8 + r][k4];
            acc[r].x += xv.x * w0.x + xv.y * w1.x + xv.z * w2.x + xv.w * w3.x;
            acc[r].y += xv.x * w0.y + xv.y * w1.y + xv.z * w2.y + xv.w * w3.y;
            acc[r].z += xv.x * w0.z + xv.y * w1.z + xv.z * w2.z + xv.w * w3.z;
            acc[r].w += xv.x * w0.w + xv.y * w1.w + xv.z * w2.w + xv.w * w3.w;
        }
    }
#pragma unroll
    for (int r = 0; r < 8; ++r) {
        int row = row0 + grp * 8 + r;
        if (row < N) {
            float sc = dinv[row];
            float4 o = acc[r];
            o.x *= sc; o.y *= sc; o.z *= sc; o.w *= sc;
            ((float4*)g)[(size_t)row * 32 + lane] = o;
        }
    }
}

// ---------- fused aggregate + bias + LayerNorm + ReLU ----------
__global__ __launch_bounds__(256) void k_agg_ln(const float* __restrict__ g, const int* __restrict__ srcidx,
                                                const int* __restrict__ rowptr, const int* __restrict__ cnt,
                                                const float* __restrict__ dinv, const float* __restrict__ bias,
                                                const float* __restrict__ gamma, const float* __restrict__ beta,
                                                float* __restrict__ out, int N) {
    int wid = (int)((blockIdx.x * 256u + threadIdx.x) >> 6);
    int lane = threadIdx.x & 63;
    if (wid >= N) return;
    const float2* g2 = (const float2*)g;
    float2 self = g2[(size_t)wid * 64 + lane];
    float ax = self.x, ay = self.y;
    int start = rowptr[wid];
    int end = start + cnt[wid];
    int e = start;
    for (; e + 4 <= end; e += 4) {
        int j0 = srcidx[e], j1 = srcidx[e + 1], j2 = srcidx[e + 2], j3 = srcidx[e + 3];
        float2 a0 = g2[(size_t)j0 * 64 + lane];
        float2 a1 = g2[(size_t)j1 * 64 + lane];
        float2 a2 = g2[(size_t)j2 * 64 + lane];
        float2 a3 = g2[(size_t)j3 * 64 + lane];
        ax += (a0.x + a1.x) + (a2.x + a3.x);
        ay += (a0.y + a1.y) + (a2.y + a3.y);
    }
    for (; e < end; ++e) {
        int j = srcidx[e];
        float2 a = g2[(size_t)j * 64 + lane];
        ax += a.x;
        ay += a.y;
    }
    float di = dinv[wid];
    int c0 = lane * 2;
    float vx = ax * di + bias[c0];
    float vy = ay * di + bias[c0 + 1];
    float sum = vx + vy, sq = vx * vx + vy * vy;
#pragma unroll
    for (int off = 32; off > 0; off >>= 1) {
        sum += __shfl_xor(sum, off, 64);
        sq += __shfl_xor(sq, off, 64);
    }
    float mu = sum * (1.0f / 128.0f);
    float var = sq * (1.0f / 128.0f) - mu * mu;
    float rstd = rsqrtf(var + LN_EPS);
    float o0 = fmaxf((vx - mu) * rstd * gamma[c0] + beta[c0], 0.f);
    float o1 = fmaxf((vy - mu) * rstd * gamma[c0 + 1] + beta[c0 + 1], 0.f);
    ((float2*)out)[(size_t)wid * 64 + lane] = make_float2(o0, o1);
}

extern "C" void kernel_launch(void* const* d_in, const int* in_sizes, int n_in,
                              void* d_out, int out_size, void* d_ws, size_t ws_size,
                              hipStream_t stream) {
    const float* x = (const float*)d_in[0];
    const int* ei = (const int*)d_in[1];
    const float* W = (const float*)d_in[2];
    const float* bias = (const float*)d_in[3];
    const float* gamma = (const float*)d_in[4];
    const float* beta = (const float*)d_in[5];
    float* out = (float*)d_out;

    int N = in_sizes[0] / 128;
    int E = in_sizes[1] / 2;
    int NBUCK = (N + 255) / 256;

    char* p = (char*)d_ws;
    auto alloc = [&](size_t bytes) {
        char* r = p;
        p += (bytes + 255) & ~(size_t)255;
        return r;
    };
    int* cnt = (int*)alloc((size_t)N * 4);
    int* rowptr = (int*)alloc((size_t)N * 4);
    float* dinv = (float*)alloc((size_t)N * 4);
    int* bucketCnt = (int*)alloc(512 * 4);
    int* bucketOfs = (int*)alloc(513 * 4);
    int* bucketCursor = (int*)alloc(512 * 4);
    int* srcidx = (int*)alloc((size_t)E * 4);
    float* gbuf = (float*)alloc((size_t)N * 128 * 4);
    unsigned* pk = (unsigned*)gbuf;              // alias: pk dead before k_gemm writes gbuf

    const int NBLK = 256;
    int chunk = (E + NBLK - 1) / NBLK;

    k_zero<<<2, 256, 0, stream>>>(bucketCnt, 512);
    k_bucket_hist<<<NBLK, 256, 0, stream>>>(ei, bucketCnt, E, chunk);
    k_scan_buckets<<<1, 512, 0, stream>>>(bucketCnt, bucketOfs, bucketCursor, NBUCK, E);
    k_partition<<<NBLK, 256, 0, stream>>>(ei, bucketCursor, pk, E, chunk);
    k_csr<<<NBUCK, 256, 0, stream>>>(pk, bucketOfs, cnt, rowptr, dinv, srcidx, N);
    k_gemm<<<(N + 63) / 64, 256, 0, stream>>>(x, W, dinv, gbuf, N);
    k_agg_ln<<<(N + 3) / 4, 256, 0, stream>>>(gbuf, srcidx, rowptr, cnt, dinv, bias, gamma, beta, out, N);
}

// Round 4
// 278.118 us; speedup vs baseline: 2.5897x; 1.1615x over previous
//
#include <hip/hip_runtime.h>
#include <hip/hip_bf16.h>
#include <math.h>

#define LN_EPS 1e-5f
// Bucket = 256 destination nodes. Requires N <= 2^20 (src packs in 20 bits)
// and NBUCK <= 512. N=100k -> NBUCK=391. [problem-fixed]

typedef __attribute__((ext_vector_type(8))) short short8;
typedef __attribute__((ext_vector_type(4))) float floatx4;

__global__ __launch_bounds__(256) void k_zero(int* p, int n) {
    int i = blockIdx.x * 256 + threadIdx.x;
    if (i < n) p[i] = 0;
}

// ---- Phase A: bucket histogram (LDS-staged) ----
__global__ __launch_bounds__(256) void k_bucket_hist(const int* __restrict__ ei, int* __restrict__ bucketCnt,
                                                     int E, int chunk) {
    __shared__ int h[512];
    for (int i = threadIdx.x; i < 512; i += 256) h[i] = 0;
    __syncthreads();
    int e0 = blockIdx.x * chunk;
    int e1 = min(e0 + chunk, E);
    for (int e = e0 + threadIdx.x; e < e1; e += 256)
        atomicAdd(&h[ei[E + e] >> 8], 1);
    __syncthreads();
    for (int i = threadIdx.x; i < 512; i += 256)
        if (h[i]) atomicAdd(&bucketCnt[i], h[i]);
}

__global__ __launch_bounds__(512) void k_scan_buckets(const int* __restrict__ bucketCnt, int* __restrict__ bucketOfs,
                                                      int* __restrict__ bucketCursor, int NBUCK, int E) {
    __shared__ int s[512];
    int t = threadIdx.x;
    int v = (t < NBUCK) ? bucketCnt[t] : 0;
    s[t] = v;
    __syncthreads();
    int val = v;
    for (int off = 1; off < 512; off <<= 1) {
        int add = (t >= off) ? s[t - off] : 0;
        __syncthreads();
        val += add;
        s[t] = val;
        __syncthreads();
    }
    if (t < NBUCK) {
        int ex = val - v;
        bucketOfs[t] = ex;
        bucketCursor[t] = ex;
    }
    if (t == 0) bucketOfs[NBUCK] = E;
}

// ---- Phase B: partition edges into bucket regions, packed (dstLocal<<20)|src ----
__global__ __launch_bounds__(256) void k_partition(const int* __restrict__ ei, int* __restrict__ bucketCursor,
                                                   unsigned* __restrict__ pk, int E, int chunk) {
    __shared__ int h[512];
    __shared__ int base[512];
    for (int i = threadIdx.x; i < 512; i += 256) h[i] = 0;
    __syncthreads();
    int e0 = blockIdx.x * chunk;
    int e1 = min(e0 + chunk, E);
    for (int e = e0 + threadIdx.x; e < e1; e += 256)
        atomicAdd(&h[ei[E + e] >> 8], 1);
    __syncthreads();
    for (int i = threadIdx.x; i < 512; i += 256) {
        if (h[i] > 0) {
            base[i] = atomicAdd(&bucketCursor[i], h[i]);
            h[i] = 0;
        }
    }
    __syncthreads();
    for (int e = e0 + threadIdx.x; e < e1; e += 256) {
        int col = ei[E + e];
        int src = ei[e];
        int b = col >> 8;
        int r = atomicAdd(&h[b], 1);
        pk[base[b] + r] = ((unsigned)(col & 255) << 20) | (unsigned)src;
    }
}

// ---- Phase C: bucket -> CSR (contiguous writes), plus cnt/rowptr/dinv ----
__global__ __launch_bounds__(256) void k_csr(const unsigned* __restrict__ pk, const int* __restrict__ bucketOfs,
                                             int* __restrict__ cnt, int* __restrict__ rowptr,
                                             float* __restrict__ dinv, int* __restrict__ srcidx, int N) {
    __shared__ int lcnt[256];
    __shared__ int lofs[256];
    __shared__ int s[256];
    int b = blockIdx.x;
    int t = threadIdx.x;
    int node0 = b << 8;
    int ofs = bucketOfs[b];
    int cntb = bucketOfs[b + 1] - ofs;
    lcnt[t] = 0;
    __syncthreads();
    for (int e = t; e < cntb; e += 256)
        atomicAdd(&lcnt[pk[ofs + e] >> 20], 1);
    __syncthreads();
    int v = lcnt[t];
    s[t] = v;
    __syncthreads();
    int val = v;
    for (int off = 1; off < 256; off <<= 1) {
        int add = (t >= off) ? s[t - off] : 0;
        __syncthreads();
        val += add;
        s[t] = val;
        __syncthreads();
    }
    lofs[t] = val - v;
    int node = node0 + t;
    if (node < N) {
        cnt[node] = v;
        rowptr[node] = ofs + lofs[t];
        dinv[node] = rsqrtf((float)(v + 1));
    }
    lcnt[t] = 0;
    __syncthreads();
    for (int e = t; e < cntb; e += 256) {
        unsigned pv = pk[ofs + e];
        int d = pv >> 20;
        int r = atomicAdd(&lcnt[d], 1);
        srcidx[ofs + lofs[d] + r] = (int)(pv & 0xFFFFFu);
    }
}

// ---- W (fp32 [k][n]) -> Wt (bf16 [n][k], B-fragment friendly) ----
__global__ __launch_bounds__(256) void k_cvtW(const float* __restrict__ W, __hip_bfloat16* __restrict__ Wt) {
    int i = blockIdx.x * 256 + threadIdx.x;   // 16384 total
    int n = i >> 7, k = i & 127;
    Wt[i] = __float2bfloat16(W[k * 128 + n]);
}

// ---- g = bf16((x @ W) * dinv[row]) via MFMA 16x16x32 bf16 ----
// block = 256 thr = 4 waves; block computes 16 rows x 128 cols; wave wv does col tiles 2wv,2wv+1.
// A: lane holds x[row0 + (lane&15)][kc*32 + (lane>>4)*8 + j]  (fp32 load + cvt, L1-hot across waves)
// B: lane holds Wt[n][k] with n = tile*16 + (lane&15), k contiguous  (32 KB, L1/L2-resident)
// C/D: col = lane&15, row = (lane>>4)*4 + reg
__global__ __launch_bounds__(256) void k_gemm(const float* __restrict__ x, const __hip_bfloat16* __restrict__ Wt,
                                              const float* __restrict__ dinv, __hip_bfloat16* __restrict__ g, int N) {
    int tid = threadIdx.x;
    int lane = tid & 63;
    int wv = tid >> 6;
    int q = lane >> 4;
    int m = lane & 15;
    int row0 = blockIdx.x * 16;
    if (row0 >= N) return;
    int arow = min(row0 + m, N - 1);
    const float* xr = x + (size_t)arow * 128;
    const __hip_bfloat16* w0p = Wt + (size_t)(wv * 32 + m) * 128;
    const __hip_bfloat16* w1p = w0p + 16 * 128;
    floatx4 acc0 = {0.f, 0.f, 0.f, 0.f};
    floatx4 acc1 = {0.f, 0.f, 0.f, 0.f};
#pragma unroll
    for (int kc = 0; kc < 4; ++kc) {
        int k0 = kc * 32 + q * 8;
        float4 xa = *(const float4*)(xr + k0);
        float4 xb = *(const float4*)(xr + k0 + 4);
        union { short8 s; __hip_bfloat16 h[8]; } a;
        a.h[0] = __float2bfloat16(xa.x); a.h[1] = __float2bfloat16(xa.y);
        a.h[2] = __float2bfloat16(xa.z); a.h[3] = __float2bfloat16(xa.w);
        a.h[4] = __float2bfloat16(xb.x); a.h[5] = __float2bfloat16(xb.y);
        a.h[6] = __float2bfloat16(xb.z); a.h[7] = __float2bfloat16(xb.w);
        short8 b0 = *(const short8*)(w0p + k0);
        short8 b1 = *(const short8*)(w1p + k0);
        acc0 = __builtin_amdgcn_mfma_f32_16x16x32_bf16(a.s, b0, acc0, 0, 0, 0);
        acc1 = __builtin_amdgcn_mfma_f32_16x16x32_bf16(a.s, b1, acc1, 0, 0, 0);
    }
#pragma unroll
    for (int i = 0; i < 4; ++i) {
        int row = row0 + q * 4 + i;
        if (row < N) {
            float s = dinv[row];                 // pre-scale: g = h * dinv
            __hip_bfloat16* gp = g + (size_t)row * 128 + wv * 32;
            gp[m]      = __float2bfloat16(acc0[i] * s);
            gp[16 + m] = __float2bfloat16(acc1[i] * s);
        }
    }
}

// ---------- fused aggregate + bias + LayerNorm + ReLU (bf16 gather) ----------
// one wave per node; lane owns 2 channels packed in one u32 (2x bf16). 256 B per row gather.
__global__ __launch_bounds__(256) void k_agg_ln(const __hip_bfloat16* __restrict__ g, const int* __restrict__ srcidx,
                                                const int* __restrict__ rowptr, const int* __restrict__ cnt,
                                                const float* __restrict__ dinv, const float* __restrict__ bias,
                                                const float* __restrict__ gamma, const float* __restrict__ beta,
                                                float* __restrict__ out, int N) {
    int wid = (int)((blockIdx.x * 256u + threadIdx.x) >> 6);
    int lane = threadIdx.x & 63;
    if (wid >= N) return;
    const unsigned* g1 = (const unsigned*)g;     // u32 = channels {2*lane, 2*lane+1}
    unsigned sv = g1[(size_t)wid * 64 + lane];
    float ax = __uint_as_float(sv << 16);
    float ay = __uint_as_float(sv & 0xFFFF0000u);
    int start = rowptr[wid];
    int end = start + cnt[wid];
    int e = start;
    for (; e + 4 <= end; e += 4) {               // 4 gathers in flight
        int j0 = srcidx[e], j1 = srcidx[e + 1], j2 = srcidx[e + 2], j3 = srcidx[e + 3];
        unsigned v0 = g1[(size_t)j0 * 64 + lane];
        unsigned v1 = g1[(size_t)j1 * 64 + lane];
        unsigned v2 = g1[(size_t)j2 * 64 + lane];
        unsigned v3 = g1[(size_t)j3 * 64 + lane];
        ax += (__uint_as_float(v0 << 16) + __uint_as_float(v1 << 16)) +
              (__uint_as_float(v2 << 16) + __uint_as_float(v3 << 16));
        ay += (__uint_as_float(v0 & 0xFFFF0000u) + __uint_as_float(v1 & 0xFFFF0000u)) +
              (__uint_as_float(v2 & 0xFFFF0000u) + __uint_as_float(v3 & 0xFFFF0000u));
    }
    for (; e < end; ++e) {
        unsigned v = g1[(size_t)srcidx[e] * 64 + lane];
        ax += __uint_as_float(v << 16);
        ay += __uint_as_float(v & 0xFFFF0000u);
    }
    float di = dinv[wid];
    int c0 = lane * 2;
    float vx = ax * di + bias[c0];
    float vy = ay * di + bias[c0 + 1];
    float sum = vx + vy, sq = vx * vx + vy * vy;
#pragma unroll
    for (int off = 32; off > 0; off >>= 1) {
        sum += __shfl_xor(sum, off, 64);
        sq += __shfl_xor(sq, off, 64);
    }
    float mu = sum * (1.0f / 128.0f);
    float var = sq * (1.0f / 128.0f) - mu * mu;
    float rstd = rsqrtf(var + LN_EPS);
    float o0 = fmaxf((vx - mu) * rstd * gamma[c0] + beta[c0], 0.f);
    float o1 = fmaxf((vy - mu) * rstd * gamma[c0 + 1] + beta[c0 + 1], 0.f);
    ((float2*)out)[(size_t)wid * 64 + lane] = make_float2(o0, o1);
}

extern "C" void kernel_launch(void* const* d_in, const int* in_sizes, int n_in,
                              void* d_out, int out_size, void* d_ws, size_t ws_size,
                              hipStream_t stream) {
    const float* x = (const float*)d_in[0];
    const int* ei = (const int*)d_in[1];
    const float* W = (const float*)d_in[2];
    const float* bias = (const float*)d_in[3];
    const float* gamma = (const float*)d_in[4];
    const float* beta = (const float*)d_in[5];
    float* out = (float*)d_out;

    int N = in_sizes[0] / 128;
    int E = in_sizes[1] / 2;
    int NBUCK = (N + 255) / 256;

    char* p = (char*)d_ws;
    auto alloc = [&](size_t bytes) {
        char* r = p;
        p += (bytes + 255) & ~(size_t)255;
        return r;
    };
    int* cnt = (int*)alloc((size_t)N * 4);
    int* rowptr = (int*)alloc((size_t)N * 4);
    float* dinv = (float*)alloc((size_t)N * 4);
    int* bucketCnt = (int*)alloc(512 * 4);
    int* bucketOfs = (int*)alloc(513 * 4);
    int* bucketCursor = (int*)alloc(512 * 4);
    __hip_bfloat16* Wt = (__hip_bfloat16*)alloc(128 * 128 * 2);
    int* srcidx = (int*)alloc((size_t)E * 4);
    __hip_bfloat16* gbuf = (__hip_bfloat16*)alloc((size_t)N * 128 * 2);
    unsigned* pk = (unsigned*)gbuf;              // alias: pk (E*4 <= N*256) dead before k_gemm writes gbuf

    const int NBLK = 256;
    int chunk = (E + NBLK - 1) / NBLK;

    k_zero<<<2, 256, 0, stream>>>(bucketCnt, 512);
    k_bucket_hist<<<NBLK, 256, 0, stream>>>(ei, bucketCnt, E, chunk);
    k_scan_buckets<<<1, 512, 0, stream>>>(bucketCnt, bucketOfs, bucketCursor, NBUCK, E);
    k_partition<<<NBLK, 256, 0, stream>>>(ei, bucketCursor, pk, E, chunk);
    k_csr<<<NBUCK, 256, 0, stream>>>(pk, bucketOfs, cnt, rowptr, dinv, srcidx, N);
    k_cvtW<<<64, 256, 0, stream>>>(W, Wt);
    k_gemm<<<(N + 15) / 16, 256, 0, stream>>>(x, Wt, dinv, gbuf, N);
    k_agg_ln<<<(N + 3) / 4, 256, 0, stream>>>(gbuf, srcidx, rowptr, cnt, dinv, bias, gamma, beta, out, N);
}